// Round 7
// baseline (376.983 us; speedup 1.0000x reference)
//
#include <hip/hip_runtime.h>

#define S 2048
#define Dh 64
#define NH 16
#define SD (S*Dh)                 // 131072 elements per head plane
#define SSZ ((size_t)S*(size_t)S) // attention matrix elements per head

typedef __attribute__((ext_vector_type(4))) float f32x4;
typedef __attribute__((ext_vector_type(16))) float f32x16;
typedef __attribute__((ext_vector_type(8))) short s16x8;
typedef __attribute__((ext_vector_type(4))) unsigned int u32x4;

// workspace layout (byte offsets)
#define WSB_QSUM 0                          // 1024 f32 (4 KB)
#define WSB_RINV 4096                       // 16*2048 f32 (128 KB)
#define WSB_MASK 135168                     // bm_t: [32 kt][2048 q] u64 (512 KB)
#define WSB_QS   659456                     // NH*SD bf16 (4 MB)
#define WSB_KS   (WSB_QS + 4194304)
#define WSB_VT   (WSB_KS + 4194304)         // ends ~12.6 MB

__device__ __forceinline__ ushort f2bf(float x) {
    unsigned u = __builtin_bit_cast(unsigned, x);
    u = (u + 0x7fffu + ((u >> 16) & 1u)) >> 16;
    return (ushort)u;
}

// async 16B global -> LDS (linear dest: wave base + lane*16)
__device__ __forceinline__ void gload_lds16(const ushort* g, ushort* l) {
    __builtin_amdgcn_global_load_lds(
        (const __attribute__((address_space(1))) unsigned int*)(const void*)g,
        (__attribute__((address_space(3))) unsigned int*)(void*)l,
        16, 0, 0);
}

// ---- Q column-softmax denominators: sum_s exp(q[h,s,d]) per (head,d) ------
__global__ void k_qsum(const float* __restrict__ q, float* __restrict__ qsum) {
    const int head  = blockIdx.x >> 5;
    const int chunk = blockIdx.x & 31;       // 64 s-values per chunk
    const int t = threadIdx.x;
    const int d = t & 63, sg = t >> 6;
    const float* qh = q + (size_t)head * SD;
    const int s0 = chunk * 64;
    float acc = 0.f;
#pragma unroll
    for (int i = 0; i < 16; ++i) {
        int s = s0 + sg + 4 * i;
        acc += __expf(qh[s * Dh + d]);
    }
    __shared__ float part[4][64];
    part[sg][d] = acc;
    __syncthreads();
    if (sg == 0)
        atomicAdd(&qsum[head * 64 + d], part[0][d] + part[1][d] + part[2][d] + part[3][d]);
}

// ---- Qs = exp(q)/colsum -> bf16 ------------------------------------------
__global__ void k_qnorm(const float* __restrict__ q, const float* __restrict__ qsum,
                        ushort* __restrict__ Qs) {
    const int gid = blockIdx.x * 256 + threadIdx.x;
    const int i0 = gid * 8;
    const int head = i0 >> 17;
    const int d0 = i0 & 63;
    const float4 a = ((const float4*)(q + i0))[0];
    const float4 b = ((const float4*)(q + i0))[1];
    const float* qs = qsum + head * 64 + d0;
    s16x8 o;
    o[0] = (short)f2bf(__expf(a.x) / qs[0]);
    o[1] = (short)f2bf(__expf(a.y) / qs[1]);
    o[2] = (short)f2bf(__expf(a.z) / qs[2]);
    o[3] = (short)f2bf(__expf(a.w) / qs[3]);
    o[4] = (short)f2bf(__expf(b.x) / qs[4]);
    o[5] = (short)f2bf(__expf(b.y) / qs[5]);
    o[6] = (short)f2bf(__expf(b.z) / qs[6]);
    o[7] = (short)f2bf(__expf(b.w) / qs[7]);
    *(s16x8*)(Qs + i0) = o;
}

// ---- K softmax over heads axis (8 values) -> bf16 ------------------------
__global__ void k_ksoft(const float* __restrict__ kin, ushort* __restrict__ Ks) {
    const int gid = blockIdx.x * 256 + threadIdx.x;
    const int n = gid >> 17;
    const int rem = gid & (SD - 1);
    const float* base = kin + (size_t)n * 8 * SD + rem;
    float x[8];
    float sum = 0.f;
#pragma unroll
    for (int h = 0; h < 8; ++h) { x[h] = __expf(base[(size_t)h * SD]); sum += x[h]; }
    const float inv = 1.f / sum;
    ushort* ob = Ks + (size_t)n * 8 * SD + rem;
#pragma unroll
    for (int h = 0; h < 8; ++h) ob[(size_t)h * SD] = f2bf(x[h] * inv);
}

// ---- V transpose per head: [k][d] f32 -> Vt[d][k] bf16 -------------------
__global__ void k_vt(const float* __restrict__ V, ushort* __restrict__ Vt) {
    const int head = blockIdx.x >> 5, kt = blockIdx.x & 31;
    const int t = threadIdx.x;
    __shared__ float sv[64 * 68];
    const float4* src = (const float4*)(V + (size_t)head * SD + (size_t)kt * 64 * 64);
#pragma unroll
    for (int i = 0; i < 4; ++i) {
        int idx = t + 256 * i;
        int row = idx >> 4, c4 = idx & 15;
        *(float4*)&sv[row * 68 + c4 * 4] = src[idx];
    }
    __syncthreads();
    const int d = t >> 2, seg = t & 3;
    s16x8 v0, v1;
#pragma unroll
    for (int j = 0; j < 8; ++j) v0[j] = (short)f2bf(sv[(seg * 16 + j) * 68 + d]);
#pragma unroll
    for (int j = 0; j < 8; ++j) v1[j] = (short)f2bf(sv[(seg * 16 + 8 + j) * 68 + d]);
    ushort* dst = Vt + (size_t)head * SD + (size_t)d * S + kt * 64 + seg * 16;
    *(s16x8*)dst = v0;
    *(s16x8*)(dst + 8) = v1;
}

// ---- mask int32 [S][S] -> TRANSPOSED bitmask bm_t[kt][q] uint64 ----------
__global__ void k_mask(const int* __restrict__ mask, unsigned long long* __restrict__ bmt) {
    const int t = threadIdx.x;
    const int g = blockIdx.x * 4 + (t >> 6);   // wave id 0..4095
    const int lane = t & 63;
#pragma unroll
    for (int it = 0; it < 16; ++it) {
        int w = g * 16 + it;                   // w = q*32 + kt
        int m = mask[(size_t)w * 64 + lane];
        unsigned long long b = __ballot(m != 0);
        if (lane == 0) bmt[(size_t)(w & 31) * S + (w >> 5)] = b;
    }
}

// ---- pass A: rowsum + normalized ctx -------------------------------------
// 32x32x16 MFMA rebuild: block = 32 q, mega-tile = 128 k (16 iters), 4 waves
// each own a 32-k quarter. Swapped operands: QK = mfma(K,Q) -> D[k][q],
// q = lane&31, lane holds 16 k of its own q-row. P is packed to bf16 pairs
// IN REGISTERS and redistributed across the hi-halves with 4 shfl_xor(32)
// into exact B-fragments for PV = mfma(V,P). Zero P LDS traffic; 8
// ds_read_b128 per wave per 128k (vs 18 before). Single-buffered 32 KB
// staging, 2 barriers per mega-tile. Epilogue: 4-way k-quarter merge via
// stride-36 LDS, position-wise in (lane,reg) space.
__global__ __launch_bounds__(256, 4) void k_ctx(
        const ushort* __restrict__ Qs, const ushort* __restrict__ Ks,
        const ushort* __restrict__ Vt, const unsigned long long* __restrict__ bmt,
        float* __restrict__ ctx, float* __restrict__ rinv) {
    const int head = blockIdx.x, qt = blockIdx.y;
    const int q0 = qt * 32;
    const int t = threadIdx.x;
    const int lane = t & 63, w = t >> 6;       // w = k-quarter
    const int ql = lane & 31, hi = lane >> 5;
    const int q = q0 + ql;

    __shared__ __align__(16) char smem[37504];
    ushort* sK = (ushort*)smem;                 // [128 k][64 d], 8 swizzled 16B chunks/row
    ushort* sV = (ushort*)(smem + 16384);       // [64 d][128 k], 16 swizzled chunks/row
    float* redo  = (float*)smem;                // [4][64][36] f32 epilogue (aliases staging)
    float* redrs = (float*)(smem + 36864);      // [4][32]
    float* sInv  = (float*)(smem + 37376);      // [32]

    const ushort* Qb = Qs + (size_t)head * SD;
    const ushort* Kb = Ks + (size_t)head * SD;
    const ushort* Vb = Vt + (size_t)head * SD;

    // Q B-fragments in registers: bq[s] = Q[q][16s + 8hi + {0..7}]
    s16x8 bq[4];
#pragma unroll
    for (int s = 0; s < 4; ++s)
        bq[s] = *(const s16x8*)(Qb + (size_t)q * 64 + 16 * s + 8 * hi);

    f32x16 o0, o1;
#pragma unroll
    for (int r = 0; r < 16; ++r) { o0[r] = 0.f; o1[r] = 0.f; }
    float rs = 0.f;

    for (int mt = 0; mt < 16; ++mt) {
        const int k0 = mt * 128;
        __syncthreads();                       // prev tile consumed / epilogue-safe
#pragma unroll
        for (int i = 0; i < 4; ++i) {          // stage K: 128 rows x 8 chunks
            const int idx = t + 256 * i;
            const int row = idx >> 3, c = idx & 7;
            gload_lds16(Kb + (size_t)(k0 + row) * 64 + ((c ^ (row & 7)) * 8), &sK[idx * 8]);
        }
#pragma unroll
        for (int i = 0; i < 4; ++i) {          // stage V: 64 rows x 16 chunks
            const int idx = t + 256 * i;
            const int row = idx >> 4, c = idx & 15;
            gload_lds16(Vb + (size_t)row * S + k0 + ((c ^ (row & 7)) * 8), &sV[idx * 8]);
        }
        __syncthreads();                       // barrier drains vmcnt -> tile ready

        // QK^T (swapped): A = K rows (own quarter), B = Q regs. D[k][q].
        f32x16 sc;
#pragma unroll
        for (int r = 0; r < 16; ++r) sc[r] = 0.f;
        const int arow = 32 * w + ql;
#pragma unroll
        for (int s = 0; s < 4; ++s) {
            const s16x8 ak = *(const s16x8*)&sK[arow * 64 + (((2 * s + hi) ^ (arow & 7)) * 8)];
            sc = __builtin_amdgcn_mfma_f32_32x32x16_bf16(ak, bq[s], sc, 0, 0, 0);
        }

        // mask bits for this wave's 32-k quarter (one u64 word, half used)
        const unsigned long long m64 = bmt[(size_t)(2 * mt + (w >> 1)) * S + q];
        const unsigned mbits = (w & 1) ? (unsigned)(m64 >> 32) : (unsigned)m64;

        // masked exp + bf16 pair-pack; k(r,hi) = (r&3) + 8*(r>>2) + 4*hi
        unsigned pk8[8];
        float rsum = 0.f;
#pragma unroll
        for (int g = 0; g < 8; ++g) {
            const int r0 = 2 * g;
            const int kb = (r0 & 3) + 8 * (r0 >> 2) + 4 * hi;
            const float e0 = ((mbits >> kb) & 1u) ? __expf(sc[r0]) : 0.f;
            const float e1 = ((mbits >> (kb + 1)) & 1u) ? __expf(sc[r0 + 1]) : 0.f;
            rsum += e0 + e1;
            pk8[g] = ((unsigned)f2bf(e1) << 16) | (unsigned)f2bf(e0);
        }
        rsum += __shfl_xor(rsum, 32);          // partner hi holds complementary 16 k
        rs += rsum;

        // redistribute across hi-halves -> exact PV B-fragments (in-register)
        const unsigned x1 = __shfl_xor(hi ? pk8[0] : pk8[2], 32);
        const unsigned x2 = __shfl_xor(hi ? pk8[1] : pk8[3], 32);
        const unsigned x3 = __shfl_xor(hi ? pk8[4] : pk8[6], 32);
        const unsigned x4 = __shfl_xor(hi ? pk8[5] : pk8[7], 32);
        const u32x4 w0 = hi ? (u32x4){x1, x2, pk8[2], pk8[3]}
                            : (u32x4){pk8[0], pk8[1], x1, x2};
        const u32x4 w1 = hi ? (u32x4){x3, x4, pk8[6], pk8[7]}
                            : (u32x4){pk8[4], pk8[5], x3, x4};
        const s16x8 pb0 = __builtin_bit_cast(s16x8, w0);
        const s16x8 pb1 = __builtin_bit_cast(s16x8, w1);

        // PV (swapped): A = V rows (d), B = P frags; accumulate over own 32 k
#pragma unroll
        for (int cs = 0; cs < 2; ++cs) {
            const s16x8 pbv = cs ? pb1 : pb0;
            {
                const int vrow = ql;
                const int ch = (4 * w + 2 * cs + hi) ^ (vrow & 7);
                const s16x8 av = *(const s16x8*)&sV[vrow * 128 + ch * 8];
                o0 = __builtin_amdgcn_mfma_f32_32x32x16_bf16(av, pbv, o0, 0, 0, 0);
            }
            {
                const int vrow = 32 + ql;
                const int ch = (4 * w + 2 * cs + hi) ^ (vrow & 7);
                const s16x8 av = *(const s16x8*)&sV[vrow * 128 + ch * 8];
                o1 = __builtin_amdgcn_mfma_f32_32x32x16_bf16(av, pbv, o1, 0, 0, 0);
            }
        }
    }

    // epilogue: 4-way k-quarter merge (position-wise in (lane,reg) space)
    __syncthreads();                           // last tile consumed; alias redo
    {
        float* dst = &redo[(w * 64 + lane) * 36];
#pragma unroll
        for (int g = 0; g < 4; ++g)
            *(f32x4*)&dst[4 * g] = (f32x4){o0[4*g], o0[4*g+1], o0[4*g+2], o0[4*g+3]};
#pragma unroll
        for (int g = 0; g < 4; ++g)
            *(f32x4*)&dst[16 + 4 * g] = (f32x4){o1[4*g], o1[4*g+1], o1[4*g+2], o1[4*g+3]};
        if (hi == 0) redrs[w * 32 + ql] = rs;
    }
    __syncthreads();
    if (t < 32) {
        const float inv = 1.f / (redrs[t] + redrs[32 + t] + redrs[64 + t] + redrs[96 + t]);
        rinv[head * S + q0 + t] = inv;
        sInv[t] = inv;
    }
    __syncthreads();
#pragma unroll
    for (int cc = 0; cc < 2; ++cc) {
        const int c = t + 256 * cc;            // 0..511 = 64 lanes x 8 reg-quads
        const int l = c & 63, rq = c >> 6;
        f32x4 sum = *(const f32x4*)&redo[l * 36 + rq * 4];
#pragma unroll
        for (int ww = 1; ww < 4; ++ww)
            sum += *(const f32x4*)&redo[(ww * 64 + l) * 36 + rq * 4];
        const int qc = l & 31, hc = l >> 5;
        const int dtc = rq >> 2, rg = rq & 3;
        const int d0 = 32 * dtc + 4 * hc + 8 * rg;
        sum *= sInv[qc];
        *(f32x4*)(ctx + (size_t)head * SD + (size_t)(q0 + qc) * 64 + d0) = sum;
    }
}

// ---- pass B: recompute scores, write normalized A (ROUND-5 VERIFIED) -----
// Double-buffered sK (1 barrier/tile) + swapped operands (masked-exp-scale
// in registers) + WAVE-PRIVATE sPf bounce to re-emit coalesced 256B-run
// nontemporal stores (no cross-wave sync on the bounce). No setprio.
__global__ __launch_bounds__(256, 4) void k_awrite(
        const ushort* __restrict__ Qs, const ushort* __restrict__ Ks,
        const unsigned long long* __restrict__ bmt, const float* __restrict__ rinv,
        float* __restrict__ A) {
    const int head = blockIdx.x, qt = blockIdx.y, kc = blockIdx.z;
    const int q0 = qt * 64;
    const int t = threadIdx.x;
    const int lane = t & 63, wv = t >> 6;
    const int lm = lane & 15, lg = lane >> 4;
    const int q = q0 + 16 * wv + lm;

    __shared__ __align__(16) char smem[33792];
    ushort* sK = (ushort*)smem;                // [2][4096] linear, swizzled content
    float* sP = (float*)(smem + 16384);        // [4 waves][16][68]

    const ushort* Qb = Qs + (size_t)head * SD;
    const ushort* Kb = Ks + (size_t)head * SD;
    float* Ah = A + (size_t)head * SSZ;

    auto stage = [&](int b, int k0) {
#pragma unroll
        for (int i = 0; i < 2; ++i) {
            const int idx = t + 256 * i;
            const int row = idx >> 3, seg = idx & 7;
            gload_lds16(Kb + (size_t)(k0 + row) * 64 + ((seg ^ (row & 7)) * 8),
                        &sK[b * 4096 + idx * 8]);
        }
    };

    s16x8 bq[2];
#pragma unroll
    for (int h = 0; h < 2; ++h)
        bq[h] = *(const s16x8*)(Qb + (size_t)q * 64 + 32 * h + 8 * lg);
    const float invr = rinv[head * S + q];
    float* sPw = &sP[wv * 16 * 68];

    stage(0, kc * 512);
    unsigned long long m64 = bmt[(size_t)(kc * 8) * S + q];
    __syncthreads();

    for (int kt8 = 0; kt8 < 8; ++kt8) {
        const int k0 = kc * 512 + kt8 * 64;
        const int cur = kt8 & 1;
        if (kt8 < 7) stage(cur ^ 1, k0 + 64);
        const unsigned long long m64n =
            (kt8 < 7) ? bmt[(size_t)((k0 >> 6) + 1) * S + q] : 0ULL;

        f32x4 sc[4];
#pragma unroll
        for (int j = 0; j < 4; ++j) sc[j] = (f32x4){0.f, 0.f, 0.f, 0.f};
#pragma unroll
        for (int h = 0; h < 2; ++h)
#pragma unroll
            for (int j = 0; j < 4; ++j) {
                s16x8 ak = *(const s16x8*)&sK[cur * 4096 + (16 * j + lm) * 64 +
                                              (((4 * h + lg) ^ (lm & 7)) * 8)];
                sc[j] = __builtin_amdgcn_mfma_f32_16x16x32_bf16(ak, bq[h], sc[j], 0, 0, 0);
            }

        // masked exp*inv in registers -> wave-private LDS row (own q = row lm)
#pragma unroll
        for (int j = 0; j < 4; ++j) {
            f32x4 pv;
#pragma unroll
            for (int r = 0; r < 4; ++r) {
                const int b = 16 * j + 4 * lg + r;
                pv[r] = ((m64 >> b) & 1ULL) ? __expf(sc[j][r]) * invr : 0.f;
            }
            *(f32x4*)&sPw[lm * 68 + 16 * j + 4 * lg] = pv;
        }
        // readback coalesced: per pass 4 rows x 256B contiguous runs
#pragma unroll
        for (int pass = 0; pass < 4; ++pass) {
            const int rr = (lane >> 4) + 4 * pass;
            f32x4 pv = *(const f32x4*)&sPw[rr * 68 + (lane & 15) * 4];
            __builtin_nontemporal_store(pv,
                (f32x4*)&Ah[(size_t)(q0 + 16 * wv + rr) * S + k0 + (lane & 15) * 4]);
        }
        __syncthreads();
        m64 = m64n;
    }
}

extern "C" void kernel_launch(void* const* d_in, const int* in_sizes, int n_in,
                              void* d_out, int out_size, void* d_ws, size_t ws_size,
                              hipStream_t stream) {
    const float* q = (const float*)d_in[0];
    const float* k = (const float*)d_in[1];
    const float* v = (const float*)d_in[2];
    const int* mask = (const int*)d_in[3];
    float* out = (float*)d_out;   // [0, NH*SD) ctx ; [NH*SD, +NH*S*S) attn weights
    char* ws = (char*)d_ws;

    float* qsum = (float*)(ws + WSB_QSUM);
    float* rinv = (float*)(ws + WSB_RINV);
    unsigned long long* bm = (unsigned long long*)(ws + WSB_MASK);
    ushort* Qs = (ushort*)(ws + WSB_QS);
    ushort* Ks = (ushort*)(ws + WSB_KS);
    ushort* Vt = (ushort*)(ws + WSB_VT);

    (void)hipMemsetAsync(d_ws, 0, 4096, stream);
    k_qsum<<<512, 256, 0, stream>>>(q, qsum);
    k_mask<<<1024, 256, 0, stream>>>(mask, bm);
    k_qnorm<<<1024, 256, 0, stream>>>(q, qsum, Qs);
    k_ksoft<<<1024, 256, 0, stream>>>(k, Ks);
    k_vt<<<512, 256, 0, stream>>>(v, Vt);
    k_ctx<<<dim3(16, 64), 256, 0, stream>>>(Qs, Ks, Vt, bm, out, rinv);
    k_awrite<<<dim3(16, 32, 4), 256, 0, stream>>>(Qs, Ks, bm, rinv, out + (size_t)NH * SD);
}